// Round 2
// baseline (103.610 us; speedup 1.0000x reference)
//
#include <hip/hip_runtime.h>

// Depth-4 path signature of [64,512,10] fp32 via time-split Chen scan.
//  K1 dx_kernel:       dx rows -> ws (padded ROWF=12, row 511 = zeros).
//  K2 sig_group_kernel: 8 time-groups x 64 steps, one lane per (b,i,j,k)
//                       chain; 8 waves/SIMD occupancy. Horner-collapsed
//                       rank-1 Chen step: ~22 FMA + 0.75 LDS instr/step,
//                       wave-uniform dx row via scalar loads from global.
//  K3 combine_kernel:  fold the 8 group signatures with Chen's identity
//                       (4/3/2/1 FMAs per level-4/3/2/1 element).

#define CH     10
#define LEN    512
#define NB     64
#define NSTEP  511
#define ROWF   12            // padded dx row (48 B)
#define GROUPS 8
#define SPG    64            // steps/group (group 7 zero-padded: exp(0)=id)
#define SIGSZ  11110         // 10 + 100 + 1000 + 10000
#define TSTR   68            // transposed LDS stride (floats): 2-way banks max
#define DXG_FLOATS (NB * LEN * ROWF)

__global__ void dx_kernel(const float* __restrict__ path, float* __restrict__ dxg) {
    int idx = blockIdx.x * blockDim.x + threadIdx.x;
    const int total = NB * LEN * ROWF;
    for (int e = idx; e < total; e += gridDim.x * blockDim.x) {
        int c   = e % ROWF;
        int row = e / ROWF;          // b*512 + s
        int s   = row % LEN;
        float v = 0.f;
        if (c < CH && s < NSTEP) {
            const float* p = path + row * CH + c;   // row*CH = (b*512+s)*10
            v = p[CH] - p[0];
        }
        dxg[e] = v;
    }
}

__global__ __launch_bounds__(256, 6)
void sig_group_kernel(const float* __restrict__ dxg, float* __restrict__ wsig) {
    __shared__ __align__(16) float dxT[CH * TSTR];   // 680 floats, transposed
    const int tid  = threadIdx.x;
    const int b    = blockIdx.x >> 5;
    const int g    = (blockIdx.x >> 2) & 7;
    const int part = blockIdx.x & 3;

    const float* drows = dxg + (b * LEN + g * SPG) * ROWF;

    // stage transposed: dxT[c][s] = dx[s][c]  (global coalesced in e)
    for (int e = tid; e < CH * SPG; e += 256) {
        int s = e / CH;
        int c = e - s * CH;
        dxT[c * TSTR + s] = drows[s * ROWF + c];
    }
    __syncthreads();

    const int id = part * 256 + tid;              // chain = i*100 + j*10 + k
    if (id < 1000) {
        const int ci = id / 100, cj = (id / 10) % 10, ck = id % 10;
        float a1 = 0.f, a2 = 0.f, a3 = 0.f, a4[10];
        #pragma unroll
        for (int l = 0; l < 10; ++l) a4[l] = 0.f;

        for (int s = 0; s < SPG; s += 4) {
            // lane-indexed reads, 4 steps per ds_read_b128 (aligned: 68%4==0)
            const float4 di = *(const float4*)(dxT + ci * TSTR + s);
            const float4 dj = *(const float4*)(dxT + cj * TSTR + s);
            const float4 dk = *(const float4*)(dxT + ck * TSTR + s);
            #pragma unroll
            for (int u = 0; u < 4; ++u) {
                // wave-uniform row -> scalar loads (s is uniform, base uniform)
                const float* row = drows + (s + u) * ROWF;
                const float r0 = row[0], r1 = row[1], r2 = row[2], r3 = row[3];
                const float r4 = row[4], r5 = row[5], r6 = row[6], r7 = row[7];
                const float r8 = row[8], r9 = row[9];
                const float dxi = (&di.x)[u];
                const float dxj = (&dj.x)[u];
                const float dxk = (&dk.x)[u];

                const float p1 = a1 * (1.f / 6.f) + dxi * (1.f / 24.f);
                const float q1 = a1 * 0.5f        + dxi * (1.f / 6.f);
                const float rr = a1               + dxi * 0.5f;
                const float p2 = a2 * 0.5f + p1 * dxj;
                const float q2 = a2        + q1 * dxj;
                a2 += rr * dxj;
                const float p3 = a3 + p2 * dxk;
                a3 += q2 * dxk;
                a1 += dxi;

                a4[0] += p3 * r0; a4[1] += p3 * r1;
                a4[2] += p3 * r2; a4[3] += p3 * r3;
                a4[4] += p3 * r4; a4[5] += p3 * r5;
                a4[6] += p3 * r6; a4[7] += p3 * r7;
                a4[8] += p3 * r8; a4[9] += p3 * r9;
            }
        }

        float* wb = wsig + (b * GROUPS + g) * SIGSZ;
        float* w4 = wb + 1110 + id * 10;
        #pragma unroll
        for (int l = 0; l < 10; ++l) w4[l] = a4[l];
        wb[110 + id] = a3;
        if (ck == 0)            wb[10 + ci * 10 + cj] = a2;
        if (ck == 0 && cj == 0) wb[ci] = a1;
    }
}

__global__ __launch_bounds__(256, 1)
void combine_kernel(const float* __restrict__ wsig, float* __restrict__ out) {
    __shared__ float Bs[1110];                  // B1[10] B2[100] B3[1000]
    const int tid  = threadIdx.x;
    const int b    = blockIdx.x >> 2;
    const int part = blockIdx.x & 3;
    const int id   = part * 256 + tid;
    const bool active = id < 1000;
    const int ci = id / 100, cj = (id / 10) % 10, ck = id % 10;

    const float* w0 = wsig + (b * GROUPS) * SIGSZ;
    float a1 = 0.f, a2 = 0.f, a3 = 0.f, a4[10];
    #pragma unroll
    for (int l = 0; l < 10; ++l) a4[l] = 0.f;
    if (active) {
        a1 = w0[ci];
        a2 = w0[10 + ci * 10 + cj];
        a3 = w0[110 + id];
        #pragma unroll
        for (int l = 0; l < 10; ++l) a4[l] = w0[1110 + id * 10 + l];
    }

    for (int g = 1; g < GROUPS; ++g) {
        const float* wg = w0 + g * SIGSZ;
        __syncthreads();                       // protect Bs reuse
        for (int e = tid; e < 1110; e += 256) Bs[e] = wg[e];
        __syncthreads();
        if (active) {
            float b4[10];
            #pragma unroll
            for (int l = 0; l < 10; ++l) b4[l] = wg[1110 + id * 10 + l];
            const float* B1 = Bs;
            const float* B2 = Bs + 10;
            const float* B3 = Bs + 110;
            // level 4 first (uses old a1..a3)
            #pragma unroll
            for (int l = 0; l < 10; ++l)
                a4[l] += a3 * B1[l] + a2 * B2[ck * 10 + l]
                       + a1 * B3[(cj * 10 + ck) * 10 + l] + b4[l];
            a3 += a2 * B1[ck] + a1 * B2[cj * 10 + ck] + B3[(ci * 10 + cj) * 10 + ck];
            a2 += a1 * B1[cj] + B2[ci * 10 + cj];
            a1 += B1[ci];
        }
    }

    if (active) {
        float* ob = out + b * SIGSZ;
        float* o4 = ob + 1110 + id * 10;
        #pragma unroll
        for (int l = 0; l < 10; ++l) o4[l] = a4[l];
        ob[110 + id] = a3;
        if (ck == 0)            ob[10 + ci * 10 + cj] = a2;
        if (ck == 0 && cj == 0) ob[ci] = a1;
    }
}

extern "C" void kernel_launch(void* const* d_in, const int* in_sizes, int n_in,
                              void* d_out, int out_size, void* d_ws, size_t ws_size,
                              hipStream_t stream) {
    const float* path = (const float*)d_in[0];   // [64,512,10] fp32
    float* out  = (float*)d_out;                 // [64,11110] fp32
    float* dxg  = (float*)d_ws;                  // [64][512][12]
    float* wsig = dxg + DXG_FLOATS;              // [64][8][11110]  (~22.7 MB)

    dx_kernel<<<dim3(1536), dim3(256), 0, stream>>>(path, dxg);
    sig_group_kernel<<<dim3(NB * GROUPS * 4), dim3(256), 0, stream>>>(dxg, wsig);
    combine_kernel<<<dim3(NB * 4), dim3(256), 0, stream>>>(wsig, out);
}